// Round 2
// baseline (189.175 us; speedup 1.0000x reference)
//
#include <hip/hip_runtime.h>
#include <math.h>

// SVD++ scoring, R8: XCD-sliced L2-resident gather.
// Evidence (R6/R7): two different designs both ~41-43 us for the gather with
// FETCH_SIZE ~93 MB at 2.26 TB/s, VALUBusy 19% -> wall is random-256B-granule
// traffic on the L2<-LLC path (25.6 MB table >> 4 MB per-XCD L2).
// Fix: slice item space by (idx & 7). Block bid runs on XCD bid%8 [perf
// heuristic], and block (b, k=bid&7) accumulates only rows of segment b with
// idx&7==k. Per-XCD slice working set = 3.2 MB < 4 MB L2 -> gathers become L2
// hits. The 8x-redundant streams (flat indices, item rows, user rows, biases)
// use nontemporal loads so they do NOT evict the resident imp slice.
// Qualifying lanes are compacted (ballot+popc+ds_permute) so gathers stay
// dense: ~2 gather instrs per 64-position super-iteration instead of 16.
// Each (b,k) wave atomically adds dot(partial_sum, i)/sqrt(n) into out[b];
// the designated slice (k == b&7) also folds in u.i + biases. One memset +
// one kernel -> minimal launch structure.

typedef float f4 __attribute__((ext_vector_type(4)));

#define WPB 4   // b's (waves) per block

template <typename T>
__device__ __forceinline__ T ntload(const T* p) {
    return __builtin_nontemporal_load(const_cast<T*>(p));
}

__global__ __launch_bounds__(256, 4) void svdpp_gather(
    const int* __restrict__ user_ids,
    const int* __restrict__ item_ids,
    const int* __restrict__ offsets,
    const int* __restrict__ flat_implicit,
    const float* __restrict__ user_emb,
    const float* __restrict__ item_emb,
    const float* __restrict__ imp_emb,
    const float* __restrict__ user_bias,
    const float* __restrict__ item_bias,
    const float* __restrict__ global_bias,
    float* __restrict__ out,
    int B, int N)
{
    const int k    = blockIdx.x & 7;   // slice id == XCD id (bid%8 mapping)
    const int jb   = blockIdx.x >> 3;
    const int wave = threadIdx.x >> 6;
    const int lane = threadIdx.x & 63;

    const int b = jb * WPB + wave;
    if (b >= B) return;

    const int sub = lane >> 4;   // 0..3: row slot within a gather batch
    const int l16 = lane & 15;   // float4 slot within a 256B row

    const int s = offsets[b];
    const int e = (b + 1 < B) ? offsets[b + 1] : N;
    const int n = e - s;

    const int item = item_ids[b];
    const bool designated = (k == (b & 7));

    // item-embedding fragment (cols 4*l16..4*l16+3), nontemporal: read by all
    // 8 slices, must not evict the L2-resident imp slice.
    const f4* item4 = (const f4*)item_emb;
    const f4  i4    = ntload(&item4[(size_t)item * 16 + l16]);

    const f4* impv = (const f4*)imp_emb;
    f4 acc = (f4)(0.f);

    for (int base = s; base < e; base += 64) {
        const int a   = base + lane;
        const int ac  = (a < e) ? a : s;               // safe (valid) index
        const int idx = ntload(&flat_implicit[ac]);    // coalesced, streamed

        // this lane's row belongs to our slice?
        const bool q = (a < e) && ((idx & 7) == k);

        const unsigned long long m = __ballot(q);
        const int cnt = __popcll(m);
        if (cnt == 0) continue;

        // compact qualifying idx values into slots 0..cnt-1 (push-permute);
        // non-qualifying lanes park their (still valid) idx at slot 63.
        const int rank = q ? __popcll(m & ((1ull << lane) - 1ull)) : 63;
        const int cidx = __builtin_amdgcn_ds_permute(rank << 2, idx);

        // dense gathers: 4 rows per instruction (16 lanes x float4 each)
        for (int t = 0; t < cnt; t += 4) {
            const int r      = t + sub;
            const int rowidx = __shfl(cidx, (r < cnt) ? r : 0, 64);
            const f4  v      = impv[(size_t)(unsigned)rowidx * 16 + l16];
            if (r < cnt) acc += v;
        }
    }

    // partial of (summed . i) / sqrt(n), spread over 64 lanes
    const float invn = (n > 0) ? (1.0f / sqrtf((float)n)) : 1.0f;
    float p = (acc.x * i4.x + acc.y * i4.y + acc.z * i4.z + acc.w * i4.w) * invn;

    // designated slice folds in u.i (16 lanes of sub 0 cover the row)
    if (designated && sub == 0) {
        const f4* user4 = (const f4*)user_emb;
        const f4 u4 = ntload(&user4[(size_t)user_ids[b] * 16 + l16]);
        p += u4.x * i4.x + u4.y * i4.y + u4.z * i4.z + u4.w * i4.w;
    }

    // full-wave butterfly reduction
    #pragma unroll
    for (int off = 32; off >= 1; off >>= 1)
        p += __shfl_xor(p, off, 64);

    if (lane == 0) {
        if (designated)
            p += ntload(&user_bias[user_ids[b]])
               + ntload(&item_bias[item])
               + ntload(&global_bias[0]);
        atomicAdd(&out[b], p);
    }
}

extern "C" void kernel_launch(void* const* d_in, const int* in_sizes, int n_in,
                              void* d_out, int out_size, void* d_ws, size_t ws_size,
                              hipStream_t stream) {
    const int*   user_ids      = (const int*)  d_in[0];
    const int*   item_ids      = (const int*)  d_in[1];
    const int*   offsets       = (const int*)  d_in[2];
    const int*   flat_implicit = (const int*)  d_in[3];
    const float* user_emb      = (const float*)d_in[4];
    const float* item_emb      = (const float*)d_in[5];
    const float* imp_emb       = (const float*)d_in[6];
    const float* user_bias     = (const float*)d_in[7];
    const float* item_bias     = (const float*)d_in[8];
    const float* global_bias   = (const float*)d_in[9];
    float* out = (float*)d_out;

    const int B = in_sizes[0];
    const int N = in_sizes[3];

    // out doubles as the atomic accumulator
    hipMemsetAsync(out, 0, (size_t)B * sizeof(float), stream);

    const int blocks = 8 * ((B + WPB - 1) / WPB);   // (b-group, slice) pairs
    svdpp_gather<<<blocks, WPB * 64, 0, stream>>>(
        user_ids, item_ids, offsets, flat_implicit,
        user_emb, item_emb, imp_emb,
        user_bias, item_bias, global_bias,
        out, B, N);
}